// Round 2
// baseline (291.122 us; speedup 1.0000x reference)
//
#include <hip/hip_runtime.h>
#include <hip/hip_bf16.h>

#define NN 50000      // nodes
#define EE 800000     // edges
#define KD 512        // IN_DIM
#define ND 256        // H*D

typedef __bf16 bf16x8 __attribute__((ext_vector_type(8)));
typedef float f32x4 __attribute__((ext_vector_type(4)));

// ---------- Kernel 1: W (512x256 f32, row-major) -> Wt (256x512 bf16, [n][k]) ----------
__global__ __launch_bounds__(256) void wt_prep_kernel(const float* __restrict__ W,
                                                      __hip_bfloat16* __restrict__ Wt) {
    __shared__ __align__(16) __hip_bfloat16 tile[64][72];
    const int bk = blockIdx.x & 7;    // 8 k-tiles of 64
    const int bn = blockIdx.x >> 3;   // 4 n-tiles of 64
    const int k0 = bk * 64, n0 = bn * 64;
    const int t = threadIdx.x;
    const int r = t >> 2;             // 0..63
    const int c = (t & 3) * 16;       // 0,16,32,48
    const float4* src = reinterpret_cast<const float4*>(W + (size_t)(k0 + r) * ND + n0 + c);
#pragma unroll
    for (int i = 0; i < 4; ++i) {
        float4 f = src[i];
        tile[c + i * 4 + 0][r] = __float2bfloat16(f.x);
        tile[c + i * 4 + 1][r] = __float2bfloat16(f.y);
        tile[c + i * 4 + 2][r] = __float2bfloat16(f.z);
        tile[c + i * 4 + 3][r] = __float2bfloat16(f.w);
    }
    __syncthreads();
    uint4* dst = reinterpret_cast<uint4*>(Wt + (size_t)(n0 + r) * KD + k0 + c);
    dst[0] = *reinterpret_cast<const uint4*>(&tile[r][c]);
    dst[1] = *reinterpret_cast<const uint4*>(&tile[r][c + 8]);
}

// ---------- Kernel 2: flags[dst[e]] = 1 via test-and-set (writes drop 800k -> ~50k) ----------
__global__ __launch_bounds__(256) void flag_set_kernel(const int* __restrict__ dst_idx,
                                                       unsigned char* __restrict__ flags) {
    int i = (blockIdx.x * 256 + threadIdx.x) * 4;
    if (i >= EE) return;  // EE % 4 == 0, so i+3 < EE whenever i < EE
    int4 d = *reinterpret_cast<const int4*>(dst_idx + i);
    if (flags[d.x] == 0) flags[d.x] = 1;
    if (flags[d.y] == 0) flags[d.y] = 1;
    if (flags[d.z] == 0) flags[d.z] = 1;
    if (flags[d.w] == 0) flags[d.w] = 1;
}

// ---------- Kernel 3: out[m][n] = flags[m] ? (x @ W)[m][n] : 0  (bf16 MFMA, reg-prefetch) ----------
// Block: 256 threads (4 waves). Block tile 64(M) x 256(N), BK=64, 8 K-iters.
// Wave w handles n in [w*64, w*64+64): 4x4 tiles of 16x16x32 MFMA.
// Pipeline: next k-tile's A/B global loads are issued right after the staging
// barrier so their latency overlaps the MFMA phase (m97 lesson: keep loads in
// flight across compute).
__global__ __launch_bounds__(256) void gemm_mask_kernel(const float* __restrict__ x,
                                                        const __hip_bfloat16* __restrict__ Wt,
                                                        const unsigned char* __restrict__ flags,
                                                        float* __restrict__ out) {
    __shared__ __align__(16) __hip_bfloat16 As[64 * 72];   // [m][k], pad 72
    __shared__ __align__(16) __hip_bfloat16 Bs[256 * 72];  // [n][k], pad 72

    const int t = threadIdx.x;
    const int wave = t >> 6;
    const int lane = t & 63;
    const int m_base = blockIdx.x * 64;

    f32x4 acc[4][4];
#pragma unroll
    for (int i = 0; i < 4; ++i)
#pragma unroll
        for (int j = 0; j < 4; ++j) acc[i][j] = (f32x4){0.f, 0.f, 0.f, 0.f};

    // A staging coords: thread loads 16 consecutive k (4 float4) of one row
    const int ar = t >> 2;            // 0..63 (m within tile)
    const int ac = (t & 3) * 16;      // 0,16,32,48 (k within BK)
    int arow = m_base + ar;
    if (arow >= NN) arow = NN - 1;    // clamp (stores are guarded)
    const float* aptr = x + (size_t)arow * KD + ac;

    // B staging coords: thread loads 16B chunk bc of rows bn0 + j*32
    const int bc = t & 7;             // 0..7  (x8 bf16)
    const int bn0 = t >> 3;           // 0..31
    const __hip_bfloat16* bptr = Wt + (size_t)bn0 * KD + bc * 8;

    // fragment coords (16x16x32 bf16): A[m=lane&15][k=(lane>>4)*8+j]
    const int fm = lane & 15;
    const int fk = (lane >> 4) * 8;

    // ---- prologue: prefetch k-tile 0 into registers ----
    float4 g0, g1, g2, g3;
    uint4 bv[8];
    {
        const float4* a4 = reinterpret_cast<const float4*>(aptr);
        g0 = a4[0]; g1 = a4[1]; g2 = a4[2]; g3 = a4[3];
#pragma unroll
        for (int j = 0; j < 8; ++j)
            bv[j] = *reinterpret_cast<const uint4*>(bptr + (size_t)(j * 32) * KD);
    }

    for (int kt = 0; kt < 8; ++kt) {
        // ---- stage A from regs: f32 -> bf16 ----
        union { __hip_bfloat16 h[8]; uint4 u; } p0, p1;
        p0.h[0] = __float2bfloat16(g0.x); p0.h[1] = __float2bfloat16(g0.y);
        p0.h[2] = __float2bfloat16(g0.z); p0.h[3] = __float2bfloat16(g0.w);
        p0.h[4] = __float2bfloat16(g1.x); p0.h[5] = __float2bfloat16(g1.y);
        p0.h[6] = __float2bfloat16(g1.z); p0.h[7] = __float2bfloat16(g1.w);
        p1.h[0] = __float2bfloat16(g2.x); p1.h[1] = __float2bfloat16(g2.y);
        p1.h[2] = __float2bfloat16(g2.z); p1.h[3] = __float2bfloat16(g2.w);
        p1.h[4] = __float2bfloat16(g3.x); p1.h[5] = __float2bfloat16(g3.y);
        p1.h[6] = __float2bfloat16(g3.z); p1.h[7] = __float2bfloat16(g3.w);
        *reinterpret_cast<uint4*>(&As[ar * 72 + ac]) = p0.u;
        *reinterpret_cast<uint4*>(&As[ar * 72 + ac + 8]) = p1.u;
        // ---- stage B from regs ----
#pragma unroll
        for (int j = 0; j < 8; ++j)
            *reinterpret_cast<uint4*>(&Bs[(bn0 + j * 32) * 72 + bc * 8]) = bv[j];
        __syncthreads();

        // ---- prefetch next k-tile into registers (overlaps MFMA below) ----
        if (kt < 7) {
            const int k1 = (kt + 1) * 64;
            const float4* a4 = reinterpret_cast<const float4*>(aptr + k1);
            g0 = a4[0]; g1 = a4[1]; g2 = a4[2]; g3 = a4[3];
#pragma unroll
            for (int j = 0; j < 8; ++j)
                bv[j] = *reinterpret_cast<const uint4*>(bptr + (size_t)(j * 32) * KD + k1);
        }

        // ---- MFMA: 2 k-steps of 32 ----
#pragma unroll
        for (int s = 0; s < 2; ++s) {
            bf16x8 afr[4], bfr[4];
#pragma unroll
            for (int tm = 0; tm < 4; ++tm)
                afr[tm] = *reinterpret_cast<const bf16x8*>(&As[(tm * 16 + fm) * 72 + s * 32 + fk]);
#pragma unroll
            for (int tn = 0; tn < 4; ++tn)
                bfr[tn] = *reinterpret_cast<const bf16x8*>(&Bs[(wave * 64 + tn * 16 + fm) * 72 + s * 32 + fk]);
#pragma unroll
            for (int tm = 0; tm < 4; ++tm)
#pragma unroll
                for (int tn = 0; tn < 4; ++tn)
                    acc[tm][tn] = __builtin_amdgcn_mfma_f32_16x16x32_bf16(afr[tm], bfr[tn], acc[tm][tn], 0, 0, 0);
        }
        __syncthreads();
    }

    // ---- epilogue: C/D layout col=lane&15, row=(lane>>4)*4+r; nontemporal stores ----
    const int col = lane & 15;
    const int rq = (lane >> 4) * 4;
    const int nbase = wave * 64;
#pragma unroll
    for (int tm = 0; tm < 4; ++tm) {
#pragma unroll
        for (int r = 0; r < 4; ++r) {
            const int m = m_base + tm * 16 + rq + r;
            if (m < NN) {
                const float fl = (float)flags[m];
                float* orow = out + (size_t)m * ND + nbase + col;
#pragma unroll
                for (int tn = 0; tn < 4; ++tn)
                    __builtin_nontemporal_store(acc[tm][tn][r] * fl, orow + tn * 16);
            }
        }
    }
}

extern "C" void kernel_launch(void* const* d_in, const int* in_sizes, int n_in,
                              void* d_out, int out_size, void* d_ws, size_t ws_size,
                              hipStream_t stream) {
    const float* x = (const float*)d_in[0];          // (N, 512) f32
    const int* edge_index = (const int*)d_in[1];     // (2, E) i32: row0=src, row1=dst
    const float* W = (const float*)d_in[3];          // (512, 256) f32
    float* out = (float*)d_out;                      // (N, 256) f32

    unsigned char* flags = (unsigned char*)d_ws;                       // NN bytes
    __hip_bfloat16* Wt = (__hip_bfloat16*)((char*)d_ws + 65536);       // 256 KB

    hipMemsetAsync(flags, 0, NN, stream);
    wt_prep_kernel<<<32, 256, 0, stream>>>(W, Wt);
    flag_set_kernel<<<(EE / 4 + 255) / 256, 256, 0, stream>>>(edge_index + EE, flags);
    gemm_mask_kernel<<<(NN + 63) / 64, 256, 0, stream>>>(x, Wt, flags, out);
}

// Round 3
// 288.985 us; speedup vs baseline: 1.0074x; 1.0074x over previous
//
#include <hip/hip_runtime.h>
#include <hip/hip_bf16.h>

#define NN 50000      // nodes
#define EE 800000     // edges
#define KD 512        // IN_DIM
#define ND 256        // H*D

typedef __bf16 bf16x8 __attribute__((ext_vector_type(8)));
typedef float f32x4 __attribute__((ext_vector_type(4)));

// ---------- Kernel 1: fused  (a) W (512x256 f32) -> Wt (256x512 bf16 [n][k])
//                             (b) zero the flags array (replaces hipMemsetAsync)
__global__ __launch_bounds__(256) void prep_kernel(const float* __restrict__ W,
                                                   __hip_bfloat16* __restrict__ Wt,
                                                   unsigned char* __restrict__ flags) {
    if (blockIdx.x >= 32) {
        // flags zeroing: 50000 B = 3125 uint4; blocks 32..44, 256 thr each
        int idx = (blockIdx.x - 32) * 256 + threadIdx.x;
        if (idx < 3125) reinterpret_cast<uint4*>(flags)[idx] = (uint4){0, 0, 0, 0};
        return;
    }
    __shared__ __align__(16) __hip_bfloat16 tile[64][72];
    const int bk = blockIdx.x & 7;    // 8 k-tiles of 64
    const int bn = blockIdx.x >> 3;   // 4 n-tiles of 64
    const int k0 = bk * 64, n0 = bn * 64;
    const int t = threadIdx.x;
    const int r = t >> 2;             // 0..63
    const int c = (t & 3) * 16;       // 0,16,32,48
    const float4* src = reinterpret_cast<const float4*>(W + (size_t)(k0 + r) * ND + n0 + c);
#pragma unroll
    for (int i = 0; i < 4; ++i) {
        float4 f = src[i];
        tile[c + i * 4 + 0][r] = __float2bfloat16(f.x);
        tile[c + i * 4 + 1][r] = __float2bfloat16(f.y);
        tile[c + i * 4 + 2][r] = __float2bfloat16(f.z);
        tile[c + i * 4 + 3][r] = __float2bfloat16(f.w);
    }
    __syncthreads();
    uint4* dst = reinterpret_cast<uint4*>(Wt + (size_t)(n0 + r) * KD + k0 + c);
    dst[0] = *reinterpret_cast<const uint4*>(&tile[r][c]);
    dst[1] = *reinterpret_cast<const uint4*>(&tile[r][c + 8]);
}

// ---------- Kernel 2: flags[dst[e]] = 1 via test-and-set ----------
__global__ __launch_bounds__(256) void flag_set_kernel(const int* __restrict__ dst_idx,
                                                       unsigned char* __restrict__ flags) {
    int i = (blockIdx.x * 256 + threadIdx.x) * 4;
    if (i >= EE) return;  // EE % 4 == 0
    int4 d = *reinterpret_cast<const int4*>(dst_idx + i);
    if (flags[d.x] == 0) flags[d.x] = 1;
    if (flags[d.y] == 0) flags[d.y] = 1;
    if (flags[d.z] == 0) flags[d.z] = 1;
    if (flags[d.w] == 0) flags[d.w] = 1;
}

// ---------- Kernel 3: out[m][n] = flags[m] ? (x @ W)[m][n] : 0  (bf16 MFMA, reg-prefetch) ----------
// Block: 256 threads (4 waves). Block tile 64(M) x 256(N), BK=64, 8 K-iters.
// Wave w handles n in [w*64, w*64+64): 4x4 tiles of 16x16x32 MFMA.
// Next k-tile's A/B global loads issued right after the staging barrier so
// their latency overlaps the MFMA phase. Plain (cached) epilogue stores:
// nontemporal caused 3.5x write amplification (R2 post-mortem).
__global__ __launch_bounds__(256) void gemm_mask_kernel(const float* __restrict__ x,
                                                        const __hip_bfloat16* __restrict__ Wt,
                                                        const unsigned char* __restrict__ flags,
                                                        float* __restrict__ out) {
    __shared__ __align__(16) __hip_bfloat16 As[64 * 72];   // [m][k], pad 72
    __shared__ __align__(16) __hip_bfloat16 Bs[256 * 72];  // [n][k], pad 72

    const int t = threadIdx.x;
    const int wave = t >> 6;
    const int lane = t & 63;
    const int m_base = blockIdx.x * 64;

    f32x4 acc[4][4];
#pragma unroll
    for (int i = 0; i < 4; ++i)
#pragma unroll
        for (int j = 0; j < 4; ++j) acc[i][j] = (f32x4){0.f, 0.f, 0.f, 0.f};

    // A staging coords: thread loads 16 consecutive k (4 float4) of one row
    const int ar = t >> 2;            // 0..63 (m within tile)
    const int ac = (t & 3) * 16;      // 0,16,32,48 (k within BK)
    int arow = m_base + ar;
    if (arow >= NN) arow = NN - 1;    // clamp (stores are guarded)
    const float* aptr = x + (size_t)arow * KD + ac;

    // B staging coords: thread loads 16B chunk bc of rows bn0 + j*32
    const int bc = t & 7;             // 0..7  (x8 bf16)
    const int bn0 = t >> 3;           // 0..31
    const __hip_bfloat16* bptr = Wt + (size_t)bn0 * KD + bc * 8;

    // fragment coords (16x16x32 bf16): A[m=lane&15][k=(lane>>4)*8+j]
    const int fm = lane & 15;
    const int fk = (lane >> 4) * 8;

    // ---- prologue: prefetch k-tile 0 into registers ----
    float4 g0, g1, g2, g3;
    uint4 bv[8];
    {
        const float4* a4 = reinterpret_cast<const float4*>(aptr);
        g0 = a4[0]; g1 = a4[1]; g2 = a4[2]; g3 = a4[3];
#pragma unroll
        for (int j = 0; j < 8; ++j)
            bv[j] = *reinterpret_cast<const uint4*>(bptr + (size_t)(j * 32) * KD);
    }

    for (int kt = 0; kt < 8; ++kt) {
        // ---- stage A from regs: f32 -> bf16 ----
        union { __hip_bfloat16 h[8]; uint4 u; } p0, p1;
        p0.h[0] = __float2bfloat16(g0.x); p0.h[1] = __float2bfloat16(g0.y);
        p0.h[2] = __float2bfloat16(g0.z); p0.h[3] = __float2bfloat16(g0.w);
        p0.h[4] = __float2bfloat16(g1.x); p0.h[5] = __float2bfloat16(g1.y);
        p0.h[6] = __float2bfloat16(g1.z); p0.h[7] = __float2bfloat16(g1.w);
        p1.h[0] = __float2bfloat16(g2.x); p1.h[1] = __float2bfloat16(g2.y);
        p1.h[2] = __float2bfloat16(g2.z); p1.h[3] = __float2bfloat16(g2.w);
        p1.h[4] = __float2bfloat16(g3.x); p1.h[5] = __float2bfloat16(g3.y);
        p1.h[6] = __float2bfloat16(g3.z); p1.h[7] = __float2bfloat16(g3.w);
        *reinterpret_cast<uint4*>(&As[ar * 72 + ac]) = p0.u;
        *reinterpret_cast<uint4*>(&As[ar * 72 + ac + 8]) = p1.u;
        // ---- stage B from regs ----
#pragma unroll
        for (int j = 0; j < 8; ++j)
            *reinterpret_cast<uint4*>(&Bs[(bn0 + j * 32) * 72 + bc * 8]) = bv[j];
        __syncthreads();

        // ---- prefetch next k-tile into registers (overlaps MFMA below) ----
        if (kt < 7) {
            const int k1 = (kt + 1) * 64;
            const float4* a4 = reinterpret_cast<const float4*>(aptr + k1);
            g0 = a4[0]; g1 = a4[1]; g2 = a4[2]; g3 = a4[3];
#pragma unroll
            for (int j = 0; j < 8; ++j)
                bv[j] = *reinterpret_cast<const uint4*>(bptr + (size_t)(j * 32) * KD + k1);
        }

        // ---- MFMA: 2 k-steps of 32 ----
#pragma unroll
        for (int s = 0; s < 2; ++s) {
            bf16x8 afr[4], bfr[4];
#pragma unroll
            for (int tm = 0; tm < 4; ++tm)
                afr[tm] = *reinterpret_cast<const bf16x8*>(&As[(tm * 16 + fm) * 72 + s * 32 + fk]);
#pragma unroll
            for (int tn = 0; tn < 4; ++tn)
                bfr[tn] = *reinterpret_cast<const bf16x8*>(&Bs[(wave * 64 + tn * 16 + fm) * 72 + s * 32 + fk]);
#pragma unroll
            for (int tm = 0; tm < 4; ++tm)
#pragma unroll
                for (int tn = 0; tn < 4; ++tn)
                    acc[tm][tn] = __builtin_amdgcn_mfma_f32_16x16x32_bf16(afr[tm], bfr[tn], acc[tm][tn], 0, 0, 0);
        }
        __syncthreads();
    }

    // ---- epilogue: C/D layout col=lane&15, row=(lane>>4)*4+r ----
    const int col = lane & 15;
    const int rq = (lane >> 4) * 4;
    const int nbase = wave * 64;
#pragma unroll
    for (int tm = 0; tm < 4; ++tm) {
#pragma unroll
        for (int r = 0; r < 4; ++r) {
            const int m = m_base + tm * 16 + rq + r;
            if (m < NN) {
                const float fl = (float)flags[m];
                float* orow = out + (size_t)m * ND + nbase + col;
#pragma unroll
                for (int tn = 0; tn < 4; ++tn)
                    orow[tn * 16] = acc[tm][tn][r] * fl;
            }
        }
    }
}

extern "C" void kernel_launch(void* const* d_in, const int* in_sizes, int n_in,
                              void* d_out, int out_size, void* d_ws, size_t ws_size,
                              hipStream_t stream) {
    const float* x = (const float*)d_in[0];          // (N, 512) f32
    const int* edge_index = (const int*)d_in[1];     // (2, E) i32: row0=src, row1=dst
    const float* W = (const float*)d_in[3];          // (512, 256) f32
    float* out = (float*)d_out;                      // (N, 256) f32

    unsigned char* flags = (unsigned char*)d_ws;                       // NN bytes (16B-aligned)
    __hip_bfloat16* Wt = (__hip_bfloat16*)((char*)d_ws + 65536);       // 256 KB

    prep_kernel<<<45, 256, 0, stream>>>(W, Wt, flags);                 // Wt transpose + flags zero
    flag_set_kernel<<<(EE / 4 + 255) / 256, 256, 0, stream>>>(edge_index + EE, flags);
    gemm_mask_kernel<<<(NN + 63) / 64, 256, 0, stream>>>(x, Wt, flags, out);
}

// Round 4
// 237.724 us; speedup vs baseline: 1.2246x; 1.2156x over previous
//
#include <hip/hip_runtime.h>
#include <hip/hip_bf16.h>

#define NN 50000      // nodes
#define EE 800000     // edges
#define KD 512        // IN_DIM
#define ND 256        // H*D

typedef __bf16 bf16x8 __attribute__((ext_vector_type(8)));
typedef float f32x4 __attribute__((ext_vector_type(4)));

// ---------- Kernel 1: fused  (a) W (512x256 f32) -> Wt (256x512 bf16 [n][k])
//                             (b) zero the flags array ----------
__global__ __launch_bounds__(256) void prep_kernel(const float* __restrict__ W,
                                                   __hip_bfloat16* __restrict__ Wt,
                                                   unsigned char* __restrict__ flags) {
    if (blockIdx.x >= 32) {
        int idx = (blockIdx.x - 32) * 256 + threadIdx.x;
        if (idx < 3125) reinterpret_cast<uint4*>(flags)[idx] = (uint4){0, 0, 0, 0};
        return;
    }
    __shared__ __align__(16) __hip_bfloat16 tile[64][72];
    const int bk = blockIdx.x & 7;
    const int bn = blockIdx.x >> 3;
    const int k0 = bk * 64, n0 = bn * 64;
    const int t = threadIdx.x;
    const int r = t >> 2;
    const int c = (t & 3) * 16;
    const float4* src = reinterpret_cast<const float4*>(W + (size_t)(k0 + r) * ND + n0 + c);
#pragma unroll
    for (int i = 0; i < 4; ++i) {
        float4 f = src[i];
        tile[c + i * 4 + 0][r] = __float2bfloat16(f.x);
        tile[c + i * 4 + 1][r] = __float2bfloat16(f.y);
        tile[c + i * 4 + 2][r] = __float2bfloat16(f.z);
        tile[c + i * 4 + 3][r] = __float2bfloat16(f.w);
    }
    __syncthreads();
    uint4* dst = reinterpret_cast<uint4*>(Wt + (size_t)(n0 + r) * KD + k0 + c);
    dst[0] = *reinterpret_cast<const uint4*>(&tile[r][c]);
    dst[1] = *reinterpret_cast<const uint4*>(&tile[r][c + 8]);
}

// ---------- Kernel 2: flags[dst[e]] = 1 via test-and-set ----------
__global__ __launch_bounds__(256) void flag_set_kernel(const int* __restrict__ dst_idx,
                                                       unsigned char* __restrict__ flags) {
    int i = (blockIdx.x * 256 + threadIdx.x) * 4;
    if (i >= EE) return;  // EE % 4 == 0
    int4 d = *reinterpret_cast<const int4*>(dst_idx + i);
    if (flags[d.x] == 0) flags[d.x] = 1;
    if (flags[d.y] == 0) flags[d.y] = 1;
    if (flags[d.z] == 0) flags[d.z] = 1;
    if (flags[d.w] == 0) flags[d.w] = 1;
}

// ---------- Kernel 3: out[m][n] = flags[m] ? (x @ W)[m][n] : 0 ----------
// 512 threads = 8 waves as 2(M) x 4(N). Block tile 128(M) x 256(N), BK=64.
// Each wave: 64x64 via 4x4 of 16x16x32 bf16 MFMA (same per-wave job as the
// proven R1 kernel). Load-after-barrier (short live ranges — R2/R3's held
// prefetch registers caused scratch spills: +139 MB HBM writes, 65->114 us).
// LDS 54 KB -> 2 blocks/CU = 16 waves/CU (vs 12 at BM=64).
__global__ __launch_bounds__(512, 4) void gemm_mask_kernel(const float* __restrict__ x,
                                                           const __hip_bfloat16* __restrict__ Wt,
                                                           const unsigned char* __restrict__ flags,
                                                           float* __restrict__ out) {
    __shared__ __align__(16) __hip_bfloat16 As[128 * 72];   // [m][k], pad 72
    __shared__ __align__(16) __hip_bfloat16 Bs[256 * 72];   // [n][k], pad 72

    const int t = threadIdx.x;
    const int wave = t >> 6;          // 0..7
    const int lane = t & 63;
    const int wm = wave >> 2;         // 0..1  (M half)
    const int wn = wave & 3;          // 0..3  (N quarter)
    const int m_base = blockIdx.x * 128;

    f32x4 acc[4][4];
#pragma unroll
    for (int i = 0; i < 4; ++i)
#pragma unroll
        for (int j = 0; j < 4; ++j) acc[i][j] = (f32x4){0.f, 0.f, 0.f, 0.f};

    // A staging: thread -> row ar (0..127), 16 consecutive k at ac
    const int ar = t >> 2;            // 0..127
    const int ac = (t & 3) * 16;      // 0,16,32,48
    int arow = m_base + ar;
    if (arow >= NN) arow = NN - 1;    // clamp (stores are guarded)
    const float* aptr = x + (size_t)arow * KD + ac;

    // B staging: thread -> rows bn0 + j*64 (j<4), 16B chunk bc
    const int bc = t & 7;             // 0..7 (x8 bf16)
    const int bn0 = t >> 3;           // 0..63
    const __hip_bfloat16* bptr = Wt + (size_t)bn0 * KD + bc * 8;

    // fragment coords (16x16x32 bf16): A[m=lane&15][k=(lane>>4)*8+j]
    const int fm = lane & 15;
    const int fk = (lane >> 4) * 8;

    for (int kt = 0; kt < 8; ++kt) {
        const int k0 = kt * 64;
        // ---- stage A: 128x64 f32 -> bf16 ----
        const float4* a4 = reinterpret_cast<const float4*>(aptr + k0);
        float4 g0 = a4[0], g1 = a4[1], g2 = a4[2], g3 = a4[3];
        union { __hip_bfloat16 h[8]; uint4 u; } p0, p1;
        p0.h[0] = __float2bfloat16(g0.x); p0.h[1] = __float2bfloat16(g0.y);
        p0.h[2] = __float2bfloat16(g0.z); p0.h[3] = __float2bfloat16(g0.w);
        p0.h[4] = __float2bfloat16(g1.x); p0.h[5] = __float2bfloat16(g1.y);
        p0.h[6] = __float2bfloat16(g1.z); p0.h[7] = __float2bfloat16(g1.w);
        p1.h[0] = __float2bfloat16(g2.x); p1.h[1] = __float2bfloat16(g2.y);
        p1.h[2] = __float2bfloat16(g2.z); p1.h[3] = __float2bfloat16(g2.w);
        p1.h[4] = __float2bfloat16(g3.x); p1.h[5] = __float2bfloat16(g3.y);
        p1.h[6] = __float2bfloat16(g3.z); p1.h[7] = __float2bfloat16(g3.w);
        *reinterpret_cast<uint4*>(&As[ar * 72 + ac]) = p0.u;
        *reinterpret_cast<uint4*>(&As[ar * 72 + ac + 8]) = p1.u;
        // ---- stage B: 256x64 bf16 from Wt (L2-resident) ----
#pragma unroll
        for (int j = 0; j < 4; ++j) {
            const int n = bn0 + j * 64;
            uint4 v = *reinterpret_cast<const uint4*>(bptr + (size_t)(j * 64) * KD + k0);
            *reinterpret_cast<uint4*>(&Bs[n * 72 + bc * 8]) = v;
        }
        __syncthreads();
        // ---- MFMA: 2 k-steps of 32 ----
#pragma unroll
        for (int s = 0; s < 2; ++s) {
            bf16x8 afr[4], bfr[4];
#pragma unroll
            for (int tm = 0; tm < 4; ++tm)
                afr[tm] = *reinterpret_cast<const bf16x8*>(&As[(wm * 64 + tm * 16 + fm) * 72 + s * 32 + fk]);
#pragma unroll
            for (int tn = 0; tn < 4; ++tn)
                bfr[tn] = *reinterpret_cast<const bf16x8*>(&Bs[(wn * 64 + tn * 16 + fm) * 72 + s * 32 + fk]);
#pragma unroll
            for (int tm = 0; tm < 4; ++tm)
#pragma unroll
                for (int tn = 0; tn < 4; ++tn)
                    acc[tm][tn] = __builtin_amdgcn_mfma_f32_16x16x32_bf16(afr[tm], bfr[tn], acc[tm][tn], 0, 0, 0);
        }
        __syncthreads();
    }

    // ---- epilogue: C/D layout col=lane&15, row=(lane>>4)*4+r ----
    const int col = lane & 15;
    const int rq = (lane >> 4) * 4;
    const int nbase = wn * 64;
#pragma unroll
    for (int tm = 0; tm < 4; ++tm) {
#pragma unroll
        for (int r = 0; r < 4; ++r) {
            const int m = m_base + wm * 64 + tm * 16 + rq + r;
            if (m < NN) {
                const float fl = (float)flags[m];
                float* orow = out + (size_t)m * ND + nbase + col;
#pragma unroll
                for (int tn = 0; tn < 4; ++tn)
                    orow[tn * 16] = acc[tm][tn][r] * fl;
            }
        }
    }
}

extern "C" void kernel_launch(void* const* d_in, const int* in_sizes, int n_in,
                              void* d_out, int out_size, void* d_ws, size_t ws_size,
                              hipStream_t stream) {
    const float* x = (const float*)d_in[0];          // (N, 512) f32
    const int* edge_index = (const int*)d_in[1];     // (2, E) i32: row0=src, row1=dst
    const float* W = (const float*)d_in[3];          // (512, 256) f32
    float* out = (float*)d_out;                      // (N, 256) f32

    unsigned char* flags = (unsigned char*)d_ws;                       // NN bytes (16B-aligned)
    __hip_bfloat16* Wt = (__hip_bfloat16*)((char*)d_ws + 65536);       // 256 KB

    prep_kernel<<<45, 256, 0, stream>>>(W, Wt, flags);
    flag_set_kernel<<<(EE / 4 + 255) / 256, 256, 0, stream>>>(edge_index + EE, flags);
    gemm_mask_kernel<<<(NN + 127) / 128, 512, 0, stream>>>(x, Wt, flags, out);
}